// Round 4
// baseline (141.848 us; speedup 1.0000x reference)
//
#include <hip/hip_runtime.h>
#include <hip/hip_bf16.h>
#include <math.h>

// NT-Xent loss, N=4096, D=256. LDS-free symmetric triangular MFMA version.
// loss = (1/2N) * sum_i [ 2 + log( sum_{j != i} exp(2*dot_ij - 2) ) - 2*dot(zn_i, zn_pair(i)) ]
// K1: normalize rows -> bf16 zn in ws; zero rowtotal[8192] and out.
// K2: upper-triangular 128x128 tiles (2080 blocks), 4 waves of 64x64.
//     NO LDS staging, NO main-loop barriers: A/B fragments loaded straight from
//     global (L2-resident zn) as short8, register double-buffered across the 8
//     k-slots. Fused epilogue: exp row-sums + col-sums -> rowtotal (one barrier
//     for the LDS combine), diag mask j<=i, pair tiles add -2*pair_dot to out.
// K3: loss += sum_i (2 + log(rowtotal[i])) / 2N.

using short8  = __attribute__((ext_vector_type(8))) short;
using floatx4 = __attribute__((ext_vector_type(4))) float;

constexpr int TWO_N = 8192;
constexpr int DIM   = 256;
constexpr int NB    = 64;                 // 8192/128 tiles per side
constexpr int NTRI  = NB * (NB + 1) / 2;  // 2080
constexpr float INV2N = 1.0f / 8192.0f;

__device__ static inline unsigned short f2bf(float f) {
  unsigned u = __float_as_uint(f);
  return (unsigned short)((u + 0x7fffu + ((u >> 16) & 1u)) >> 16);  // RNE
}

// ---------------- K1: normalize + cast to bf16, zero accumulators ----------------
__global__ __launch_bounds__(256) void k_normalize(
    const float* __restrict__ zi, const float* __restrict__ zj,
    __hip_bfloat16* __restrict__ zn, float* __restrict__ rowtotal,
    float* __restrict__ out)
{
  if (blockIdx.x == 0 && threadIdx.x == 0) out[0] = 0.0f;
  if (blockIdx.x < 32) rowtotal[blockIdx.x * 256 + threadIdx.x] = 0.0f;

  const int lane = threadIdx.x & 63;
  const int wave = threadIdx.x >> 6;
  const int row  = blockIdx.x * 4 + wave;
  const float* src = (row < 4096) ? (zi + (size_t)row * DIM)
                                  : (zj + (size_t)(row - 4096) * DIM);
  float4 v = reinterpret_cast<const float4*>(src)[lane];
  float ss = v.x * v.x + v.y * v.y + v.z * v.z + v.w * v.w;
#pragma unroll
  for (int m = 32; m >= 1; m >>= 1) ss += __shfl_xor(ss, m, 64);
  float inv = 1.0f / fmaxf(sqrtf(ss), 1e-8f);
  ushort4 o;
  o.x = f2bf(v.x * inv); o.y = f2bf(v.y * inv);
  o.z = f2bf(v.z * inv); o.w = f2bf(v.w * inv);
  reinterpret_cast<ushort4*>(zn + (size_t)row * DIM)[lane] = o;
}

// ---------------- K2: LDS-free triangular GEMM + fused epilogue ----------------
__global__ __launch_bounds__(256) void k_simexp(
    const __hip_bfloat16* __restrict__ Z, float* __restrict__ rowtotal,
    float* __restrict__ out)
{
  __shared__ float rowsum[2][128];   // [wn][row in tile]
  __shared__ float colsum[2][128];   // [wm][col in tile]

  const int tid  = threadIdx.x;
  const int lane = tid & 63;
  const int wave = tid >> 6;
  const int wm   = wave >> 1;
  const int wn   = wave & 1;
  const int c16  = lane & 15;
  const int q    = lane >> 4;

  // triangular decode: blockIdx.x -> (ib <= jb)
  const int u = blockIdx.x;
  int jb = (int)((sqrtf(8.0f * (float)u + 1.0f) - 1.0f) * 0.5f);
  while ((jb + 1) * (jb + 2) / 2 <= u) ++jb;
  while (jb * (jb + 1) / 2 > u) --jb;
  const int ib = u - jb * (jb + 1) / 2;

  const bool diagblk = (ib == jb);
  const bool pairblk = (jb == ib + 32);
  const int i0 = ib * 128;
  const int j0 = jb * 128;

  // fragment base pointers: lane reads row (base + mt*16) at k = s*32 + q*8
  const __hip_bfloat16* pA = Z + (size_t)(i0 + wm * 64 + c16) * DIM + q * 8;
  const __hip_bfloat16* pB = Z + (size_t)(j0 + wn * 64 + c16) * DIM + q * 8;

  floatx4 acc[4][4] = {};
  short8 a0[4], b0[4], a1[4], b1[4];

#define LOADF(A_, B_, s_)                                                     \
  do {                                                                        \
    _Pragma("unroll") for (int mt = 0; mt < 4; ++mt)                          \
        A_[mt] = *reinterpret_cast<const short8*>(pA + mt * 16 * DIM + (s_) * 32); \
    _Pragma("unroll") for (int nt = 0; nt < 4; ++nt)                          \
        B_[nt] = *reinterpret_cast<const short8*>(pB + nt * 16 * DIM + (s_) * 32); \
  } while (0)

#define MFMAF(A_, B_)                                                         \
  do {                                                                        \
    _Pragma("unroll") for (int mt = 0; mt < 4; ++mt)                          \
        _Pragma("unroll") for (int nt = 0; nt < 4; ++nt)                      \
            acc[mt][nt] = __builtin_amdgcn_mfma_f32_16x16x32_bf16(            \
                A_[mt], B_[nt], acc[mt][nt], 0, 0, 0);                        \
  } while (0)

  LOADF(a0, b0, 0);
#pragma unroll
  for (int s = 0; s < 8; s += 2) {
    if (s + 1 < 8) LOADF(a1, b1, s + 1);
    MFMAF(a0, b0);
    if (s + 2 < 8) LOADF(a0, b0, s + 2);
    MFMAF(a1, b1);
  }
#undef LOADF
#undef MFMAF

  // ---- epilogue ----
  // C/D layout: col = c16 (within nt-tile), row = q*4 + reg (within mt-tile).
  float colacc[4] = {0.f, 0.f, 0.f, 0.f};
  float pc = 0.f;
  const int ibase = i0 + wm * 64 + (q << 2);
  const int jbase = j0 + wn * 64 + c16;

#pragma unroll
  for (int mt = 0; mt < 4; ++mt) {
#pragma unroll
    for (int reg = 0; reg < 4; ++reg) {
      const int i = ibase + mt * 16 + reg;
      float s = 0.0f;
#pragma unroll
      for (int nt = 0; nt < 4; ++nt) {
        const int j = jbase + nt * 16;
        float e = __expf(2.0f * acc[mt][nt][reg] - 2.0f);
        if (diagblk && j <= i) e = 0.0f;   // strict upper triangle only
        s += e;
        colacc[nt] += e;
        if (pairblk && (j - i == 4096)) pc += acc[mt][nt][reg];
      }
      s += __shfl_xor(s, 1, 64);
      s += __shfl_xor(s, 2, 64);
      s += __shfl_xor(s, 4, 64);
      s += __shfl_xor(s, 8, 64);
      if (c16 == 0)
        rowsum[wn][wm * 64 + mt * 16 + (q << 2) + reg] = s;  // unique writer
    }
  }

#pragma unroll
  for (int nt = 0; nt < 4; ++nt) {
    float cs = colacc[nt];
    cs += __shfl_xor(cs, 16, 64);
    cs += __shfl_xor(cs, 32, 64);
    if (lane < 16) colsum[wm][wn * 64 + nt * 16 + lane] = cs;  // unique writer
  }

  if (pairblk) {
#pragma unroll
    for (int m = 32; m >= 1; m >>= 1) pc += __shfl_xor(pc, m, 64);
    // per pair: rows i and i+4096 each lose 2*dot -> -4*dot total
    if (lane == 0) atomicAdd(out, -4.0f * pc * INV2N);
  }

  __syncthreads();  // the only barrier in the kernel
  if (tid < 128) {
    atomicAdd(&rowtotal[i0 + tid], rowsum[0][tid] + rowsum[1][tid]);
    atomicAdd(&rowtotal[j0 + tid], colsum[0][tid] + colsum[1][tid]);
  }
}

// ---------------- K3: finalize (logs + reduce) ----------------
__global__ __launch_bounds__(256) void k_finalize(
    const float* __restrict__ rowtotal, float* __restrict__ out)
{
  __shared__ float wsum[4];
  const int lane = threadIdx.x & 63;
  const int wave = threadIdx.x >> 6;
  const int row  = blockIdx.x * 256 + threadIdx.x;
  float v = 2.0f + __logf(rowtotal[row]);
#pragma unroll
  for (int m = 32; m >= 1; m >>= 1) v += __shfl_xor(v, m, 64);
  if (lane == 0) wsum[wave] = v;
  __syncthreads();
  if (threadIdx.x == 0)
    atomicAdd(out, (wsum[0] + wsum[1] + wsum[2] + wsum[3]) * INV2N);
}

// ---------------- launch ----------------
extern "C" void kernel_launch(void* const* d_in, const int* in_sizes, int n_in,
                              void* d_out, int out_size, void* d_ws, size_t ws_size,
                              hipStream_t stream) {
  const float* zi = (const float*)d_in[0];
  const float* zj = (const float*)d_in[1];
  float* out = (float*)d_out;

  __hip_bfloat16* zn = (__hip_bfloat16*)d_ws;                        // 8192*256*2 = 4 MB
  float* rowtotal = (float*)((char*)d_ws + (size_t)TWO_N * DIM * 2); // 8192*4 = 32 KB

  k_normalize<<<dim3(TWO_N / 4), dim3(256), 0, stream>>>(zi, zj, zn, rowtotal, out);
  k_simexp<<<dim3(NTRI), dim3(256), 0, stream>>>(zn, rowtotal, out);
  k_finalize<<<dim3(TWO_N / 256), dim3(256), 0, stream>>>(rowtotal, out);
}